// Round 1
// baseline (1206.731 us; speedup 1.0000x reference)
//
#include <hip/hip_runtime.h>

// NLReader bidirectional LSTM, MI355X — persistent scan, fence-free relay.
//
// Round-10: x-projection hoisted OFF the serial relay chain + wave-matched
// flag polling.
//  (a) gates_x = emb @ Wih^T is step-independent -> precomputed by a pre-GEMM
//      (emb_gather converts the gathered embedding rows to bf16 once; xproj
//      computes all 128 steps x 2048 gate-cols per dir and stores f32
//      C-fragments in the scan's exact per-lane layout). The scan step head no
//      longer runs 32 MFMAs + 128 v_cvt before the poll, and the 2.1 GB of
//      in-loop table re-reads (64x duplicated per dir, ~2 TB/s of background
//      MALL traffic against the latency-critical relay) disappear.
//  (b) consumer wave w only reads h rows [16w,16w+16), written exclusively by
//      wave w of each producer block -> poll only the 64 wave-matched flags
//      (1 load/lane, 4 lines) instead of 256 (4 loads, 16 lines). WAR-safe:
//      the writer of buf[s&1] at step s+1 waits on exactly the waves that
//      read buf[s&1] at step s. Poll is software-pipelined (one flag load in
//      flight while the previous result is tested).
//  Relay protocol otherwise IDENTICAL to round-9: agent-scope (sc1, MALL)
//  h-stores, vmcnt(0) ack before flag post, one-asm-node h-fetch (16x
//  global_load_dwordx4 sc1 + s_waitcnt vmcnt(0)), f32 c-state in registers,
//  bf16 double-buffered h in ws.
//
// Workspace: needs 137 MB for xp/ebf. If ws_size is smaller, falls back to
// the verbatim round-9 kernel (lstm_scan_legacy).
//
// Block (dir=bid>>6, kb=bid&63) owns 8 hidden units as 32 permuted gate cols:
//   tile t4 in {0,1}, lane col c in [0,16): gate g = c&3, unit jj = 2*(c>>2)+t4
//   orig Wih/Whh row = g*512 + kb*8 + jj.

typedef float  f32x4  __attribute__((ext_vector_type(4)));
typedef __bf16 bf16x8 __attribute__((ext_vector_type(8)));
typedef __bf16 bf16;

#define HB_OFF   ((size_t)0)        // 4 x [64 x 512] bf16 = 262144 B
#define FLAG_OFF ((size_t)262144)   // 512 x u32 = 2048 B
#define ZROW_OFF ((size_t)264192)   // 512 f32 zero row (legacy path only)
#define WS_ZERO_BYTES ((size_t)266240)
#define XP_OFF   ((size_t)266240)                 // 128 blk*128 s*2048 f32
#define XP_BYTES ((size_t)134217728)
#define EBF_OFF  (XP_OFF + XP_BYTES)              // 8192 rows * 512 bf16
#define EBF_BYTES ((size_t)8388608)
#define WS_NEED  (EBF_OFF + EBF_BYTES)            // 142872576 B

__device__ __forceinline__ float sigmoidf_(float x) {
    return 1.0f / (1.0f + __expf(-x));
}
__device__ __forceinline__ float tanhf_(float x) {
    return 2.0f * sigmoidf_(2.0f * x) - 1.0f;
}
__device__ __forceinline__ bf16x8 cvt8(const float* p) {
    float4 a = *(const float4*)p;
    float4 b = *(const float4*)(p + 4);
    bf16x8 r;
    r[0] = (bf16)a.x; r[1] = (bf16)a.y; r[2] = (bf16)a.z; r[3] = (bf16)a.w;
    r[4] = (bf16)b.x; r[5] = (bf16)b.y; r[6] = (bf16)b.z; r[7] = (bf16)b.w;
    return r;
}
__device__ __forceinline__ bf16x8 cvt8v(uint4 u0, uint4 u1) {
    float4 a = __builtin_bit_cast(float4, u0);
    float4 b = __builtin_bit_cast(float4, u1);
    bf16x8 r;
    r[0] = (bf16)a.x; r[1] = (bf16)a.y; r[2] = (bf16)a.z; r[3] = (bf16)a.w;
    r[4] = (bf16)b.x; r[5] = (bf16)b.y; r[6] = (bf16)b.z; r[7] = (bf16)b.w;
    return r;
}

__global__ __launch_bounds__(256) void init_ws(unsigned long long* __restrict__ w) {
    const size_t i = (size_t)blockIdx.x * 256 + threadIdx.x;
    if (i < WS_ZERO_BYTES / 8) w[i] = 0ull;
}

// ---- pre-pass 1: gather + f32->bf16 embedding rows, pad rows zeroed ----
// ebf[t*64 + b][512] bf16, 1 KB per row. grid 2048 x 256 (one wave per row).
__global__ __launch_bounds__(256) void emb_gather(
    const int* __restrict__ data, const float* __restrict__ table,
    bf16* __restrict__ ebf)
{
    const int wave = threadIdx.x >> 6, lane = threadIdx.x & 63;
    const int rr = blockIdx.x * 4 + wave;          // 0..8191 = t*64+b
    const int qv = data[rr];
    bf16x8 v;
    if (qv >= 0) {
        v = cvt8(table + (size_t)qv * 512 + lane * 8);
    } else {
#pragma unroll
        for (int i = 0; i < 8; ++i) v[i] = (bf16)0.f;
    }
    *(bf16x8*)(ebf + (size_t)rr * 512 + lane * 8) = v;
}

// ---- pre-pass 2: xp = emb @ Wih^T for all steps, stored as f32 C-fragments
// in the scan's per-lane layout:
//   xp[((dir*64+kb)*128 + s)*2048 + wave*512 + (q*16+c)*8 + t4*4 + r]
// grid 128 x 256: dir = bid>>6, cc = (bid>>1)&31 (covers kb 2cc,2cc+1),
// sh = bid&1 (step half). MFMA accumulation order identical to the round-9
// in-loop x-projection (kc ascending) -> bitwise-same numerics.
__global__ __launch_bounds__(256, 1) void xproj(
    const bf16* __restrict__ ebf,
    const float* __restrict__ wih_f, const float* __restrict__ wih_b,
    float* __restrict__ xp)
{
    __shared__ bf16 sB[4096 * 8];                  // 64 KB: 64 gate cols x 512 k
    const int tid = threadIdx.x, bid = blockIdx.x;
    const int dir = bid >> 6, cc = (bid >> 1) & 31, sh = bid & 1;
    const int wave = tid >> 6, lane = tid & 63;
    const int c = lane & 15, q = lane >> 4;
    const float* wih = dir ? wih_b : wih_f;

    // stage: entry e = ekc*256 + et*64 + eq*16 + ec; et = col tile 0..3
    for (int e = tid; e < 4096; e += 256) {
        const int ec = e & 15, eq = (e >> 4) & 3, et = (e >> 6) & 3, ekc = e >> 8;
        const int kbx = 2 * cc + (et >> 1), t4x = et & 1;
        const size_t orig = (size_t)((ec & 3) * 512 + kbx * 8 + 2 * (ec >> 2) + t4x);
        *(bf16x8*)(&sB[e * 8]) = cvt8(&wih[orig * 512 + ekc * 32 + eq * 8]);
    }
    __syncthreads();

    const int hrow = 16 * wave + c;
    const f32x4 zz = {0.f, 0.f, 0.f, 0.f};
    const size_t flin = (size_t)wave * 512 + (q * 16 + c) * 8;

    for (int s0 = 0; s0 < 64; ++s0) {
        const int s = sh * 64 + s0;
        const int tt = dir ? (127 - s) : s;
        const bf16* arow = ebf + (size_t)(tt * 64 + hrow) * 512;
        uint4 af[16];
#pragma unroll
        for (int kc = 0; kc < 16; ++kc)
            af[kc] = *(const uint4*)(arow + kc * 32 + q * 8);

        f32x4 acc0 = zz, acc1 = zz, acc2 = zz, acc3 = zz;
#pragma unroll
        for (int kc = 0; kc < 16; ++kc) {
            const bf16x8 a = __builtin_bit_cast(bf16x8, af[kc]);
            acc0 = __builtin_amdgcn_mfma_f32_16x16x32_bf16(
                a, *(const bf16x8*)(&sB[(kc * 256 +   0 + q * 16 + c) * 8]), acc0, 0, 0, 0);
            acc1 = __builtin_amdgcn_mfma_f32_16x16x32_bf16(
                a, *(const bf16x8*)(&sB[(kc * 256 +  64 + q * 16 + c) * 8]), acc1, 0, 0, 0);
            acc2 = __builtin_amdgcn_mfma_f32_16x16x32_bf16(
                a, *(const bf16x8*)(&sB[(kc * 256 + 128 + q * 16 + c) * 8]), acc2, 0, 0, 0);
            acc3 = __builtin_amdgcn_mfma_f32_16x16x32_bf16(
                a, *(const bf16x8*)(&sB[(kc * 256 + 192 + q * 16 + c) * 8]), acc3, 0, 0, 0);
        }
        const size_t r0 = ((size_t)(dir * 64 + 2 * cc)     * 128 + s) * 2048 + flin;
        const size_t r1 = ((size_t)(dir * 64 + 2 * cc + 1) * 128 + s) * 2048 + flin;
        *(float4*)(&xp[r0])     = __builtin_bit_cast(float4, acc0);   // kb=2cc,  t4=0
        *(float4*)(&xp[r0 + 4]) = __builtin_bit_cast(float4, acc1);   // kb=2cc,  t4=1
        *(float4*)(&xp[r1])     = __builtin_bit_cast(float4, acc2);   // kb=2cc+1,t4=0
        *(float4*)(&xp[r1 + 4]) = __builtin_bit_cast(float4, acc3);   // kb=2cc+1,t4=1
    }
}

// ---- main persistent scan (x-projection removed, wave-matched flags) ----
// flag index = dir*256 + wave*64 + kb (consumer wave w polls its 64 wave-w
// producers in one contiguous 256 B region: 1 load/lane).
__global__ __launch_bounds__(256, 1) void lstm_scan(
    const float* __restrict__ mask,    // [128,64] f32 (0/1)
    const float* __restrict__ whh_f, const float* __restrict__ whh_b,
    const float* __restrict__ bih_f, const float* __restrict__ bhh_f,
    const float* __restrict__ bih_b, const float* __restrict__ bhh_b,
    const float* __restrict__ xp,      // precomputed x-gate fragments
    bf16* __restrict__ hbuf,           // [dir][buf][64][512] bf16 (internal)
    unsigned* __restrict__ flags,      // 512 per-wave monotone flags
    float* __restrict__ out)           // [128,64,1024] f32
{
    __shared__ bf16 sW[2048 * 8];      // Whh fragments, 32 KB

    const int tid = threadIdx.x, bid = blockIdx.x;
    const int dir = bid >> 6, kb = bid & 63;
    const int wave = tid >> 6, lane = tid & 63;
    const int c = lane & 15, q = lane >> 4, g = c & 3;

    const float* whh = dir ? whh_b : whh_f;
    const float* bih = dir ? bih_b : bih_f;
    const float* bhh = dir ? bhh_b : bhh_f;

    for (int e = tid; e < 2048; e += 256) {
        const int ec = e & 15, eq = (e >> 4) & 3, et = (e >> 6) & 1, ekc = e >> 7;
        const size_t orig = (size_t)((ec & 3) * 512 + kb * 8 + 2 * (ec >> 2) + et);
        *(bf16x8*)(&sW[e * 8]) = cvt8(&whh[orig * 512 + ekc * 32 + eq * 8]);
    }
    float bias_v[2];
#pragma unroll
    for (int t4 = 0; t4 < 2; ++t4) {
        const int orig = g * 512 + kb * 8 + 2 * (c >> 2) + t4;
        bias_v[t4] = bih[orig] + bhh[orig];
    }

    float cst[2][4] = {{0.f, 0.f, 0.f, 0.f}, {0.f, 0.f, 0.f, 0.f}};
    const int hrow = 16 * wave + c;
    const int myflag = dir * 256 + wave * 64 + kb;
    const int fidx   = dir * 256 + wave * 64 + lane;
    const f32x4 zz = {0.f, 0.f, 0.f, 0.f};
    __syncthreads();                    // sW ready; no syncs after this

    // prologue: x-gate fragment + mask for step 0
    const float* xpb = xp + (size_t)bid * 128 * 2048
                          + (size_t)wave * 512 + (q * 16 + c) * 8;
    float4 xq0 = *(const float4*)(xpb);
    float4 xq1 = *(const float4*)(xpb + 4);
    float4 mv;
    {
        const int tt0 = dir ? 127 : 0;
        mv = *(const float4*)(&mask[tt0 * 64 + 16 * wave + 4 * q]);
    }

    for (int s = 0; s < 128; ++s) {
        const int tt = dir ? (127 - s) : s;

        // ---- wait: the 64 wave-matched producer waves completed step s-1.
        // Software-pipelined: one flag load in flight while testing the last.
        const unsigned tgt = (unsigned)s;
        unsigned fa = __hip_atomic_load(flags + fidx, __ATOMIC_RELAXED, __HIP_MEMORY_SCOPE_AGENT);
        unsigned fb = __hip_atomic_load(flags + fidx, __ATOMIC_RELAXED, __HIP_MEMORY_SCOPE_AGENT);
        for (;;) {
            if (__all(fa >= tgt)) break;
            fa = fb;
            fb = __hip_atomic_load(flags + fidx, __ATOMIC_RELAXED, __HIP_MEMORY_SCOPE_AGENT);
        }
        __asm__ volatile("" ::: "memory");   // keep h-loads below the poll

        const bf16* hb = hbuf + (size_t)(dir * 2 + (s & 1)) * (64 * 512);
        bf16*       hw = hbuf + (size_t)(dir * 2 + ((s + 1) & 1)) * (64 * 512);

        // ---- h A-fragments: ONE asm node = 16 agent-scope (sc1) dwordx4
        //      loads + s_waitcnt vmcnt(0); "=&v" keeps dests off the addr pair.
        const unsigned long long ha =
            (unsigned long long)hb + (unsigned)(hrow * 1024 + q * 16);
        uint4 af[16];
        asm volatile(
            "global_load_dwordx4 %0,  %16, off sc1\n\t"
            "global_load_dwordx4 %1,  %16, off offset:64   sc1\n\t"
            "global_load_dwordx4 %2,  %16, off offset:128  sc1\n\t"
            "global_load_dwordx4 %3,  %16, off offset:192  sc1\n\t"
            "global_load_dwordx4 %4,  %16, off offset:256  sc1\n\t"
            "global_load_dwordx4 %5,  %16, off offset:320  sc1\n\t"
            "global_load_dwordx4 %6,  %16, off offset:384  sc1\n\t"
            "global_load_dwordx4 %7,  %16, off offset:448  sc1\n\t"
            "global_load_dwordx4 %8,  %16, off offset:512  sc1\n\t"
            "global_load_dwordx4 %9,  %16, off offset:576  sc1\n\t"
            "global_load_dwordx4 %10, %16, off offset:640  sc1\n\t"
            "global_load_dwordx4 %11, %16, off offset:704  sc1\n\t"
            "global_load_dwordx4 %12, %16, off offset:768  sc1\n\t"
            "global_load_dwordx4 %13, %16, off offset:832  sc1\n\t"
            "global_load_dwordx4 %14, %16, off offset:896  sc1\n\t"
            "global_load_dwordx4 %15, %16, off offset:960  sc1\n\t"
            "s_waitcnt vmcnt(0)"
            : "=&v"(af[0]),  "=&v"(af[1]),  "=&v"(af[2]),  "=&v"(af[3]),
              "=&v"(af[4]),  "=&v"(af[5]),  "=&v"(af[6]),  "=&v"(af[7]),
              "=&v"(af[8]),  "=&v"(af[9]),  "=&v"(af[10]), "=&v"(af[11]),
              "=&v"(af[12]), "=&v"(af[13]), "=&v"(af[14]), "=&v"(af[15])
            : "v"(ha)
            : "memory");

        f32x4 acc0 = zz, acc1 = zz;
#pragma unroll
        for (int kc = 0; kc < 16; ++kc) {
            const bf16x8 a  = __builtin_bit_cast(bf16x8, af[kc]);
            const bf16x8 b0 = *(const bf16x8*)(&sW[(kc * 128 + q * 16 + c) * 8]);
            const bf16x8 b1 = *(const bf16x8*)(&sW[(kc * 128 + 64 + q * 16 + c) * 8]);
            acc0 = __builtin_amdgcn_mfma_f32_16x16x32_bf16(a, b0, acc0, 0, 0, 0);
            acc1 = __builtin_amdgcn_mfma_f32_16x16x32_bf16(a, b1, acc1, 0, 0, 0);
        }

        // ---- epilogue: C/D layout col=lane&15, row=q*4+r ----
        unsigned* hw32 = (unsigned*)hw;
        float hreg[4][2];
#pragma unroll
        for (int r = 0; r < 4; ++r) {
            const int b_ = 16 * wave + 4 * q + r;
            const float m = (&mv.x)[r];
            float hv01[2];
#pragma unroll
            for (int t4 = 0; t4 < 2; ++t4) {
                float v = (t4 ? acc1[r] : acc0[r])
                        + (t4 ? (&xq1.x)[r] : (&xq0.x)[r]) + bias_v[t4];
                const float v1 = __shfl_xor(v, 1);
                const float v2 = __shfl_xor(v, 2);
                const float v3 = __shfl_xor(v, 3);
                const float gi = (g == 0) ? v  : (g == 1) ? v1 : (g == 2) ? v2 : v3;
                const float gf = (g == 0) ? v1 : (g == 1) ? v  : (g == 2) ? v3 : v2;
                const float gG = (g == 0) ? v2 : (g == 1) ? v3 : (g == 2) ? v  : v1;
                const float go = (g == 0) ? v3 : (g == 1) ? v2 : (g == 2) ? v1 : v;
                const float cn = sigmoidf_(gf) * cst[t4][r] + sigmoidf_(gi) * tanhf_(gG);
                float hv       = sigmoidf_(go) * tanhf_(cn);
                cst[t4][r] = cn * m;
                hv *= m;
                hv01[t4] = hv;
            }
            hreg[r][0] = hv01[0]; hreg[r][1] = hv01[1];
            if (g == 0) {                   // packed 2xbf16 -> one u32 sc1 store
                const unsigned u =
                    (unsigned)__builtin_bit_cast(unsigned short, (bf16)hv01[0]) |
                    ((unsigned)__builtin_bit_cast(unsigned short, (bf16)hv01[1]) << 16);
                __hip_atomic_store(hw32 + b_ * 256 + kb * 4 + (c >> 2), u,
                                   __ATOMIC_RELAXED, __HIP_MEMORY_SCOPE_AGENT);
            }
        }

        // release: all h sc1-stores acked at MALL before flag store
        __asm__ volatile("" ::: "memory");
        __builtin_amdgcn_s_waitcnt(0x0F70);  // vmcnt(0)
        if (lane == 0)
            __hip_atomic_store(flags + myflag, (unsigned)(s + 1),
                               __ATOMIC_RELAXED, __HIP_MEMORY_SCOPE_AGENT);

        // ---- step tail (hidden behind other blocks' consumption) ----
        if (g == 0) {
            const int j2 = dir * 512 + kb * 8 + 2 * (c >> 2);
#pragma unroll
            for (int r = 0; r < 4; ++r) {
                const int b_ = 16 * wave + 4 * q + r;
                float2 o2; o2.x = hreg[r][0]; o2.y = hreg[r][1];
                *(float2*)(&out[(size_t)(tt * 64 + b_) * 1024 + j2]) = o2;
            }
        }
        if (s < 127) {
            const int tt_n = dir ? (126 - s) : (s + 1);
            xq0 = *(const float4*)(xpb + (size_t)(s + 1) * 2048);
            xq1 = *(const float4*)(xpb + (size_t)(s + 1) * 2048 + 4);
            mv  = *(const float4*)(&mask[tt_n * 64 + 16 * wave + 4 * q]);
        }
    }
}

// ---- verbatim round-9 kernel: fallback if ws_size < WS_NEED ----
__global__ __launch_bounds__(256, 1) void lstm_scan_legacy(
    const int*   __restrict__ data,
    const float* __restrict__ mask,
    const float* __restrict__ table,
    const float* __restrict__ wih_f, const float* __restrict__ whh_f,
    const float* __restrict__ bih_f, const float* __restrict__ bhh_f,
    const float* __restrict__ wih_b, const float* __restrict__ whh_b,
    const float* __restrict__ bih_b, const float* __restrict__ bhh_b,
    bf16* __restrict__ hbuf,
    unsigned* __restrict__ flags,
    const float* __restrict__ zrow,
    float* __restrict__ out)
{
    __shared__ bf16 sW[2048 * 8];
    __shared__ bf16 sV[2048 * 8];

    const int tid = threadIdx.x, bid = blockIdx.x;
    const int dir = bid >> 6, kb = bid & 63;
    const int wave = tid >> 6, lane = tid & 63;
    const int c = lane & 15, q = lane >> 4, g = c & 3;

    const float* wih = dir ? wih_b : wih_f;
    const float* whh = dir ? whh_b : whh_f;
    const float* bih = dir ? bih_b : bih_f;
    const float* bhh = dir ? bhh_b : bhh_f;

    for (int e = tid; e < 2048; e += 256) {
        const int ec = e & 15, eq = (e >> 4) & 3, et = (e >> 6) & 1, ekc = e >> 7;
        const size_t orig = (size_t)((ec & 3) * 512 + kb * 8 + 2 * (ec >> 2) + et);
        const size_t off = orig * 512 + ekc * 32 + eq * 8;
        *(bf16x8*)(&sW[e * 8]) = cvt8(&whh[off]);
        *(bf16x8*)(&sV[e * 8]) = cvt8(&wih[off]);
    }
    float bias_v[2];
#pragma unroll
    for (int t4 = 0; t4 < 2; ++t4) {
        const int orig = g * 512 + kb * 8 + 2 * (c >> 2) + t4;
        bias_v[t4] = bih[orig] + bhh[orig];
    }

    float cst[2][4] = {{0.f, 0.f, 0.f, 0.f}, {0.f, 0.f, 0.f, 0.f}};
    const int hrow = 16 * wave + c;
    const int myflag = dir * 256 + kb * 4 + wave;
    const int fbase = dir * 256;
    const f32x4 zz = {0.f, 0.f, 0.f, 0.f};
    __syncthreads();

    uint4 xe[32];
    float4 mv;
    int qv_n;
    {
        const int tt0 = dir ? 127 : 0;
        const int qv0 = data[tt0 * 64 + hrow];
        mv = *(const float4*)(&mask[tt0 * 64 + 16 * wave + 4 * q]);
        const float* erow = (qv0 >= 0) ? (table + (size_t)qv0 * 512) : zrow;
#pragma unroll
        for (int kc = 0; kc < 16; ++kc) {
            xe[2 * kc]     = *(const uint4*)(erow + kc * 32 + q * 8);
            xe[2 * kc + 1] = *(const uint4*)(erow + kc * 32 + q * 8 + 4);
        }
        const int tt1 = dir ? 126 : 1;
        qv_n = data[tt1 * 64 + hrow];
    }

    for (int s = 0; s < 128; ++s) {
        const int tt = dir ? (127 - s) : s;

        f32x4 accx0 = zz, accx1 = zz;
#pragma unroll
        for (int kc = 0; kc < 16; ++kc) {
            const bf16x8 e  = cvt8v(xe[2 * kc], xe[2 * kc + 1]);
            const bf16x8 b0 = *(const bf16x8*)(&sV[(kc * 128 + q * 16 + c) * 8]);
            const bf16x8 b1 = *(const bf16x8*)(&sV[(kc * 128 + 64 + q * 16 + c) * 8]);
            accx0 = __builtin_amdgcn_mfma_f32_16x16x32_bf16(e, b0, accx0, 0, 0, 0);
            accx1 = __builtin_amdgcn_mfma_f32_16x16x32_bf16(e, b1, accx1, 0, 0, 0);
        }

        const unsigned tgt = (unsigned)s;
        for (;;) {
            const unsigned a0 = __hip_atomic_load(flags + fbase + lane,       __ATOMIC_RELAXED, __HIP_MEMORY_SCOPE_AGENT);
            const unsigned a1 = __hip_atomic_load(flags + fbase + 64  + lane, __ATOMIC_RELAXED, __HIP_MEMORY_SCOPE_AGENT);
            const unsigned a2 = __hip_atomic_load(flags + fbase + 128 + lane, __ATOMIC_RELAXED, __HIP_MEMORY_SCOPE_AGENT);
            const unsigned a3 = __hip_atomic_load(flags + fbase + 192 + lane, __ATOMIC_RELAXED, __HIP_MEMORY_SCOPE_AGENT);
            if (__all(a0 >= tgt && a1 >= tgt && a2 >= tgt && a3 >= tgt)) break;
            __builtin_amdgcn_s_sleep(1);
        }
        __asm__ volatile("" ::: "memory");

        const bf16* hb = hbuf + (size_t)(dir * 2 + (s & 1)) * (64 * 512);
        bf16*       hw = hbuf + (size_t)(dir * 2 + ((s + 1) & 1)) * (64 * 512);

        const unsigned long long ha =
            (unsigned long long)hb + (unsigned)(hrow * 1024 + q * 16);
        uint4 af[16];
        asm volatile(
            "global_load_dwordx4 %0,  %16, off sc1\n\t"
            "global_load_dwordx4 %1,  %16, off offset:64   sc1\n\t"
            "global_load_dwordx4 %2,  %16, off offset:128  sc1\n\t"
            "global_load_dwordx4 %3,  %16, off offset:192  sc1\n\t"
            "global_load_dwordx4 %4,  %16, off offset:256  sc1\n\t"
            "global_load_dwordx4 %5,  %16, off offset:320  sc1\n\t"
            "global_load_dwordx4 %6,  %16, off offset:384  sc1\n\t"
            "global_load_dwordx4 %7,  %16, off offset:448  sc1\n\t"
            "global_load_dwordx4 %8,  %16, off offset:512  sc1\n\t"
            "global_load_dwordx4 %9,  %16, off offset:576  sc1\n\t"
            "global_load_dwordx4 %10, %16, off offset:640  sc1\n\t"
            "global_load_dwordx4 %11, %16, off offset:704  sc1\n\t"
            "global_load_dwordx4 %12, %16, off offset:768  sc1\n\t"
            "global_load_dwordx4 %13, %16, off offset:832  sc1\n\t"
            "global_load_dwordx4 %14, %16, off offset:896  sc1\n\t"
            "global_load_dwordx4 %15, %16, off offset:960  sc1\n\t"
            "s_waitcnt vmcnt(0)"
            : "=&v"(af[0]),  "=&v"(af[1]),  "=&v"(af[2]),  "=&v"(af[3]),
              "=&v"(af[4]),  "=&v"(af[5]),  "=&v"(af[6]),  "=&v"(af[7]),
              "=&v"(af[8]),  "=&v"(af[9]),  "=&v"(af[10]), "=&v"(af[11]),
              "=&v"(af[12]), "=&v"(af[13]), "=&v"(af[14]), "=&v"(af[15])
            : "v"(ha)
            : "memory");

        f32x4 acc0 = zz, acc1 = zz;
#pragma unroll
        for (int kc = 0; kc < 16; ++kc) {
            const bf16x8 a  = __builtin_bit_cast(bf16x8, af[kc]);
            const bf16x8 b0 = *(const bf16x8*)(&sW[(kc * 128 + q * 16 + c) * 8]);
            const bf16x8 b1 = *(const bf16x8*)(&sW[(kc * 128 + 64 + q * 16 + c) * 8]);
            acc0 = __builtin_amdgcn_mfma_f32_16x16x32_bf16(a, b0, acc0, 0, 0, 0);
            acc1 = __builtin_amdgcn_mfma_f32_16x16x32_bf16(a, b1, acc1, 0, 0, 0);
        }

        unsigned* hw32 = (unsigned*)hw;
        float hreg[4][2];
#pragma unroll
        for (int r = 0; r < 4; ++r) {
            const int b_ = 16 * wave + 4 * q + r;
            const float m = (&mv.x)[r];
            float hv01[2];
#pragma unroll
            for (int t4 = 0; t4 < 2; ++t4) {
                float v = (t4 ? acc1[r] : acc0[r]) + (t4 ? accx1[r] : accx0[r]) + bias_v[t4];
                const float v1 = __shfl_xor(v, 1);
                const float v2 = __shfl_xor(v, 2);
                const float v3 = __shfl_xor(v, 3);
                const float gi = (g == 0) ? v  : (g == 1) ? v1 : (g == 2) ? v2 : v3;
                const float gf = (g == 0) ? v1 : (g == 1) ? v  : (g == 2) ? v3 : v2;
                const float gG = (g == 0) ? v2 : (g == 1) ? v3 : (g == 2) ? v  : v1;
                const float go = (g == 0) ? v3 : (g == 1) ? v2 : (g == 2) ? v1 : v;
                const float cn = sigmoidf_(gf) * cst[t4][r] + sigmoidf_(gi) * tanhf_(gG);
                float hv       = sigmoidf_(go) * tanhf_(cn);
                cst[t4][r] = cn * m;
                hv *= m;
                hv01[t4] = hv;
            }
            hreg[r][0] = hv01[0]; hreg[r][1] = hv01[1];
            if (g == 0) {
                const unsigned u =
                    (unsigned)__builtin_bit_cast(unsigned short, (bf16)hv01[0]) |
                    ((unsigned)__builtin_bit_cast(unsigned short, (bf16)hv01[1]) << 16);
                __hip_atomic_store(hw32 + b_ * 256 + kb * 4 + (c >> 2), u,
                                   __ATOMIC_RELAXED, __HIP_MEMORY_SCOPE_AGENT);
            }
        }

        __asm__ volatile("" ::: "memory");
        __builtin_amdgcn_s_waitcnt(0x0F70);
        if (lane == 0)
            __hip_atomic_store(flags + myflag, (unsigned)(s + 1),
                               __ATOMIC_RELAXED, __HIP_MEMORY_SCOPE_AGENT);

        if (g == 0) {
            const int j2 = dir * 512 + kb * 8 + 2 * (c >> 2);
#pragma unroll
            for (int r = 0; r < 4; ++r) {
                const int b_ = 16 * wave + 4 * q + r;
                float2 o2; o2.x = hreg[r][0]; o2.y = hreg[r][1];
                *(float2*)(&out[(size_t)(tt * 64 + b_) * 1024 + j2]) = o2;
            }
        }
        if (s < 127) {
            const int tt_n = dir ? (126 - s) : (s + 1);
            const float* erow = (qv_n >= 0) ? (table + (size_t)qv_n * 512) : zrow;
#pragma unroll
            for (int kc = 0; kc < 16; ++kc) {
                xe[2 * kc]     = *(const uint4*)(erow + kc * 32 + q * 8);
                xe[2 * kc + 1] = *(const uint4*)(erow + kc * 32 + q * 8 + 4);
            }
            mv = *(const float4*)(&mask[tt_n * 64 + 16 * wave + 4 * q]);
            if (s < 126) {
                const int tt_n2 = dir ? (125 - s) : (s + 2);
                qv_n = data[tt_n2 * 64 + hrow];
            }
        }
    }
}

extern "C" void kernel_launch(void* const* d_in, const int* in_sizes, int n_in,
                              void* d_out, int out_size, void* d_ws, size_t ws_size,
                              hipStream_t stream) {
    const int*   data  = (const int*)d_in[0];
    const float* mask  = (const float*)d_in[1];
    const float* table = (const float*)d_in[2];
    const float* wih_f = (const float*)d_in[3];
    const float* whh_f = (const float*)d_in[4];
    const float* bih_f = (const float*)d_in[5];
    const float* bhh_f = (const float*)d_in[6];
    const float* wih_b = (const float*)d_in[7];
    const float* whh_b = (const float*)d_in[8];
    const float* bih_b = (const float*)d_in[9];
    const float* bhh_b = (const float*)d_in[10];
    float* outp = (float*)d_out;

    char* ws = (char*)d_ws;
    bf16*     hbuf  = (bf16*)(ws + HB_OFF);
    unsigned* flagp = (unsigned*)(ws + FLAG_OFF);

    init_ws<<<(int)((WS_ZERO_BYTES / 8 + 255) / 256), 256, 0, stream>>>(
        (unsigned long long*)ws);

    if (ws_size >= WS_NEED) {
        bf16*  ebf = (bf16*)(ws + EBF_OFF);
        float* xp  = (float*)(ws + XP_OFF);
        emb_gather<<<2048, 256, 0, stream>>>(data, table, ebf);
        xproj<<<128, 256, 0, stream>>>(ebf, wih_f, wih_b, xp);
        lstm_scan<<<128, 256, 0, stream>>>(mask, whh_f, whh_b,
                                           bih_f, bhh_f, bih_b, bhh_b,
                                           xp, hbuf, flagp, outp);
    } else {
        const float* zrow = (const float*)(ws + ZROW_OFF);
        lstm_scan_legacy<<<128, 256, 0, stream>>>(data, mask, table,
                                                  wih_f, whh_f, bih_f, bhh_f,
                                                  wih_b, whh_b, bih_b, bhh_b,
                                                  hbuf, flagp, zrow, outp);
    }
}